// Round 2
// baseline (565.008 us; speedup 1.0000x reference)
//
#include <hip/hip_runtime.h>
#include <hip/hip_bf16.h>
#include <stdint.h>

#define NN 16384
#define DD 512
#define MARGINV 2.0f
#define EPSV 1e-6f

#define BJ 16
#define JGROUPS 4
#define JRANGE (NN / JGROUPS)   // 4096
#define NTILES (JRANGE / BJ)    // 256
#define ROWB 1040               // 1024 B row + 16 B pad (stride 65 chunks ≡ 1 mod 8 bank-groups)
#define BUFB (BJ * ROWB)

typedef __attribute__((ext_vector_type(4))) float          f32x4;
typedef __attribute__((ext_vector_type(8))) short          bf16x8;
typedef __attribute__((ext_vector_type(8))) unsigned short u16x8;

__device__ inline unsigned short f2bf(float f) {
  unsigned int u = __builtin_bit_cast(unsigned int, f);
  u += 0x7FFFu + ((u >> 16) & 1u);   // round-nearest-even
  return (unsigned short)(u >> 16);
}

// lexicographic (val, idx) insert of one candidate into a sorted-3 list
__device__ inline void ins3(float v, int ix,
                            float& b0, int& x0, float& b1, int& x1,
                            float& b2, int& x2) {
  bool l2 = (v < b2) || (v == b2 && ix < x2);
  if (l2) {
    bool l0 = (v < b0) || (v == b0 && ix < x0);
    bool l1 = (v < b1) || (v == b1 && ix < x1);
    b2 = l1 ? b1 : v;               x2 = l1 ? x1 : ix;
    b1 = l0 ? b0 : (l1 ? v : b1);   x1 = l0 ? x0 : (l1 ? ix : x1);
    b0 = l0 ? v : b0;               x0 = l0 ? ix : x0;
  }
}

// ---------------- Kernel 1: row squared norms (fp32) + bf16 copy ----------------
extern "C" __global__ __launch_bounds__(256)
void prep_kernel(const float* __restrict__ x, unsigned short* __restrict__ xb,
                 float* __restrict__ sq) {
  int row  = blockIdx.x * 4 + (threadIdx.x >> 6);
  int lane = threadIdx.x & 63;
  const float* xr = x + (size_t)row * DD + lane * 8;
  f32x4 a = *(const f32x4*)xr;
  f32x4 b = *(const f32x4*)(xr + 4);
  float s = a[0]*a[0]+a[1]*a[1]+a[2]*a[2]+a[3]*a[3]
          + b[0]*b[0]+b[1]*b[1]+b[2]*b[2]+b[3]*b[3];
  #pragma unroll
  for (int off = 1; off < 64; off <<= 1) s += __shfl_xor(s, off, 64);
  u16x8 o;
  o[0]=f2bf(a[0]); o[1]=f2bf(a[1]); o[2]=f2bf(a[2]); o[3]=f2bf(a[3]);
  o[4]=f2bf(b[0]); o[5]=f2bf(b[1]); o[6]=f2bf(b[2]); o[7]=f2bf(b[3]);
  *(u16x8*)(xb + (size_t)row * DD + lane * 8) = o;
  if (lane == 0) sq[row] = s;
}

// ---------------- Kernel 2: fused GEMM (X·X^T) + per-row top-3 ----------------
// block = 256 thr (4 waves); block covers 128 i-rows x one j-group of 4096.
// Per wave: 2 register-resident A-sets of 16 i-rows (128 VGPR) -> each LDS
// B-fragment read feeds 2 MFMAs (FLOP/LDS-byte doubled vs round 1).
// B staged 16 j-rows/tile into LDS (double-buffered) via global_load_lds w=16.
// MFMA 16x16x32 bf16; C layout col=lane&15 (j), row=quad*4+reg (i).
extern "C" __global__ __launch_bounds__(256, 2)
void knn_kernel(const unsigned short* __restrict__ xb, const float* __restrict__ sq,
                float* __restrict__ pv, int* __restrict__ pi) {
  __shared__ __align__(16) char lds[2 * BUFB];  // 33,280 B
  const int tid  = threadIdx.x;
  const int wave = tid >> 6;
  const int lane = tid & 63;
  const int quad = lane >> 4;
  const int r16  = lane & 15;
  const int bi   = blockIdx.x >> 2;             // 0..127
  const int bj   = blockIdx.x & 3;
  const int ibase  = bi * 128 + wave * 32;      // 32 i-rows per wave
  const int jbase0 = bj * JRANGE;

  // A fragments: A[m=lane&15][k=quad*8+t], 2 sets x full K=512 (16 chunks)
  bf16x8 afrag0[16], afrag1[16];
  {
    const unsigned short* ar0 = xb + (size_t)(ibase + r16)      * DD + quad * 8;
    const unsigned short* ar1 = xb + (size_t)(ibase + 16 + r16) * DD + quad * 8;
    #pragma unroll
    for (int kc = 0; kc < 16; ++kc) {
      afrag0[kc] = *(const bf16x8*)(ar0 + kc * 32);
      afrag1[kc] = *(const bf16x8*)(ar1 + kc * 32);
    }
  }

  // top-3 per (set s, reg r): idx = s*4 + r  (i = ibase + s*16 + quad*4 + r)
  float t0v[8], t1v[8], t2v[8];
  int   t0i[8], t1i[8], t2i[8];
  #pragma unroll
  for (int q = 0; q < 8; ++q) {
    t0v[q] = t1v[q] = t2v[q] = 3.0e38f;
    t0i[q] = t1i[q] = t2i[q] = 0x7FFFFFFF;
  }

  auto stage = [&](int jt, int buf) {
    const int jrow0 = jbase0 + jt * BJ;
    #pragma unroll
    for (int q = 0; q < 4; ++q) {
      const int rr = wave + q * 4;                       // wave-uniform row id
      const unsigned short* gsrc = xb + (size_t)(jrow0 + rr) * DD + lane * 8;
      char* ldst = lds + buf * BUFB + rr * ROWB;         // wave-uniform LDS base
      __builtin_amdgcn_global_load_lds((__attribute__((address_space(1))) void*)gsrc,
                                       (__attribute__((address_space(3))) void*)ldst,
                                       16, 0, 0);
    }
  };

  stage(0, 0);
  for (int jt = 0; jt < NTILES; ++jt) {
    __syncthreads();                                     // staged jt ready; jt-1 compute done
    if (jt + 1 < NTILES) stage(jt + 1, (jt + 1) & 1);
    const char* brow = lds + (jt & 1) * BUFB + r16 * ROWB + quad * 16;
    f32x4 acc0 = {0.f, 0.f, 0.f, 0.f};
    f32x4 acc1 = {0.f, 0.f, 0.f, 0.f};
    #pragma unroll
    for (int kc = 0; kc < 16; ++kc) {
      bf16x8 bfrag = *(const bf16x8*)(brow + kc * 64);
      acc0 = __builtin_amdgcn_mfma_f32_16x16x32_bf16(afrag0[kc], bfrag, acc0, 0, 0, 0);
      acc1 = __builtin_amdgcn_mfma_f32_16x16x32_bf16(afrag1[kc], bfrag, acc1, 0, 0, 0);
    }
    const int j   = jbase0 + jt * BJ + r16;              // this lane's column
    const float sqj = sq[j];
    #pragma unroll
    for (int r = 0; r < 4; ++r) {
      float val = fmaf(-2.0f, acc0[r], sqj);
      if (val < t2v[r]) {                                // strict < : earliest j wins ties
        bool lt0 = val < t0v[r];
        bool lt1 = val < t1v[r];
        t2v[r] = lt1 ? t1v[r] : val;  t2i[r] = lt1 ? t1i[r] : j;
        t1v[r] = lt0 ? t0v[r] : (lt1 ? val : t1v[r]);
        t1i[r] = lt0 ? t0i[r] : (lt1 ? j   : t1i[r]);
        t0v[r] = lt0 ? val : t0v[r];  t0i[r] = lt0 ? j : t0i[r];
      }
    }
    #pragma unroll
    for (int r = 0; r < 4; ++r) {
      float val = fmaf(-2.0f, acc1[r], sqj);
      int q = 4 + r;
      if (val < t2v[q]) {
        bool lt0 = val < t0v[q];
        bool lt1 = val < t1v[q];
        t2v[q] = lt1 ? t1v[q] : val;  t2i[q] = lt1 ? t1i[q] : j;
        t1v[q] = lt0 ? t0v[q] : (lt1 ? val : t1v[q]);
        t1i[q] = lt0 ? t0i[q] : (lt1 ? j   : t1i[q]);
        t0v[q] = lt0 ? val : t0v[q];  t0i[q] = lt0 ? j : t0i[q];
      }
    }
  }

  // ------- in-register butterfly merge across r16 (quad-preserving xor 1,2,4,8) -------
  #pragma unroll
  for (int m = 1; m <= 8; m <<= 1) {
    #pragma unroll
    for (int q = 0; q < 8; ++q) {
      float ov0 = __shfl_xor(t0v[q], m, 64); int oi0 = __shfl_xor(t0i[q], m, 64);
      float ov1 = __shfl_xor(t1v[q], m, 64); int oi1 = __shfl_xor(t1i[q], m, 64);
      float ov2 = __shfl_xor(t2v[q], m, 64); int oi2 = __shfl_xor(t2i[q], m, 64);
      ins3(ov0, oi0, t0v[q], t0i[q], t1v[q], t1i[q], t2v[q], t2i[q]);
      ins3(ov1, oi1, t0v[q], t0i[q], t1v[q], t1i[q], t2v[q], t2i[q]);
      ins3(ov2, oi2, t0v[q], t0i[q], t1v[q], t1i[q], t2v[q], t2i[q]);
    }
  }

  // lane with r16 == q writes row q's merged top-3 (8 parallel writers per wave)
  #pragma unroll
  for (int q = 0; q < 8; ++q) {
    if (r16 == q) {
      int s  = q >> 2, r = q & 3;
      int gi = ibase + s * 16 + quad * 4 + r;
      int ob = (gi * JGROUPS + bj) * 3;
      pv[ob+0] = t0v[q]; pv[ob+1] = t1v[q]; pv[ob+2] = t2v[q];
      pi[ob+0] = t0i[q]; pi[ob+1] = t1i[q]; pi[ob+2] = t2i[q];
    }
  }
}

// ---------------- Kernel 3: merge partials, fp32 norms, hinge, mean ----------------
extern "C" __global__ __launch_bounds__(256)
void finalize_kernel(const float* __restrict__ x, const float* __restrict__ pos,
                     const float* __restrict__ pv, const int* __restrict__ pi,
                     float* __restrict__ out) {
  __shared__ float wsum[4];
  int i    = blockIdx.x * 4 + (threadIdx.x >> 6);
  int wave = threadIdx.x >> 6;
  int lane = threadIdx.x & 63;
  int neg = 0;
  if (lane == 0) {
    float b0 = 3.0e38f, b1 = 3.0e38f, b2 = 3.0e38f;
    int   x0 = 0x7FFFFFFF, x1 = 0x7FFFFFFF, x2 = 0x7FFFFFFF;
    #pragma unroll
    for (int s = 0; s < JGROUPS * 3; ++s) {
      float v  = pv[i * (JGROUPS * 3) + s];
      int   ix = pi[i * (JGROUPS * 3) + s];
      ins3(v, ix, b0, x0, b1, x1, b2, x2);
    }
    neg = x2;   // 3rd-smallest distance (self is rank 0) -> 2nd NN
  }
  neg = __shfl(neg, 0, 64);
  const float* xr = x   + (size_t)i * DD + lane * 8;
  const float* pr = pos + (size_t)i * DD + lane * 8;
  const float* nr = x   + (size_t)neg * DD + lane * 8;
  f32x4 xa = *(const f32x4*)xr, xb4 = *(const f32x4*)(xr + 4);
  f32x4 pa = *(const f32x4*)pr, pb  = *(const f32x4*)(pr + 4);
  f32x4 na = *(const f32x4*)nr, nb  = *(const f32x4*)(nr + 4);
  float sap = 0.f, san = 0.f;
  #pragma unroll
  for (int k = 0; k < 4; ++k) {
    float d0 = xa[k]  - pa[k] + EPSV; sap = fmaf(d0, d0, sap);
    float d1 = xa[k]  - na[k] + EPSV; san = fmaf(d1, d1, san);
    float d2 = xb4[k] - pb[k] + EPSV; sap = fmaf(d2, d2, sap);
    float d3 = xb4[k] - nb[k] + EPSV; san = fmaf(d3, d3, san);
  }
  #pragma unroll
  for (int off = 1; off < 64; off <<= 1) {
    sap += __shfl_xor(sap, off, 64);
    san += __shfl_xor(san, off, 64);
  }
  if (lane == 0) {
    float l = sqrtf(sap) - sqrtf(san) + MARGINV;
    wsum[wave] = l > 0.f ? l : 0.f;
  }
  __syncthreads();
  if (threadIdx.x == 0) {
    atomicAdd(out, (wsum[0] + wsum[1] + wsum[2] + wsum[3]) * (1.0f / NN));
  }
}

// ---------------- host ----------------
extern "C" void kernel_launch(void* const* d_in, const int* in_sizes, int n_in,
                              void* d_out, int out_size, void* d_ws, size_t ws_size,
                              hipStream_t stream) {
  const float* x   = (const float*)d_in[0];
  const float* pos = (const float*)d_in[1];
  char* ws = (char*)d_ws;
  unsigned short* xb = (unsigned short*)ws;                              // 16 MB
  float* sq = (float*)(ws + (size_t)NN * DD * 2);                        // 64 KB
  float* pv = (float*)(ws + (size_t)NN * DD * 2 + (size_t)NN * 4);       // 768 KB
  int*   pi = (int*)  (ws + (size_t)NN * DD * 2 + (size_t)NN * 4
                          + (size_t)NN * JGROUPS * 3 * 4);               // 768 KB

  hipMemsetAsync(d_out, 0, sizeof(float), stream);
  prep_kernel<<<NN / 4, 256, 0, stream>>>(x, xb, sq);
  knn_kernel<<<(NN / 128) * JGROUPS, 256, 0, stream>>>(xb, sq, pv, pi);
  finalize_kernel<<<NN / 4, 256, 0, stream>>>(x, pos, pv, pi, (float*)d_out);
}

// Round 3
// 358.797 us; speedup vs baseline: 1.5747x; 1.5747x over previous
//
#include <hip/hip_runtime.h>
#include <hip/hip_bf16.h>
#include <hip/hip_fp8.h>
#include <stdint.h>

#define NN 16384
#define DD 512
#define MARGINV 2.0f
#define EPSV 1e-6f
#define INFV 3.0e38f

#define BJ 16
#define JGROUPS 8
#define JRANGE (NN / JGROUPS)   // 2048
#define NTILES (JRANGE / BJ)    // 128
#define ROWQ 512                // fp8 row bytes
#define TILEB (BJ * ROWQ)       // 8192 B per tile buffer

typedef __attribute__((ext_vector_type(4))) float f32x4;
typedef __attribute__((ext_vector_type(2))) long  l2;   // 16 B = ds_read_b128

// lexicographic (val, idx) insert into a sorted-2 list
__device__ inline void ins2(float v, int ix, float& b0, int& x0, float& b1, int& x1) {
  bool l1 = (v < b1) || (v == b1 && ix < x1);
  if (l1) {
    bool l0 = (v < b0) || (v == b0 && ix < x0);
    b1 = l0 ? b0 : v;  x1 = l0 ? x0 : ix;
    b0 = l0 ? v : b0;  x0 = l0 ? ix : x0;
  }
}

// ---------------- Kernel 1: row squared norms (fp32) + fp8 e4m3 quantize ----------------
extern "C" __global__ __launch_bounds__(256)
void prep_kernel(const float* __restrict__ x, unsigned char* __restrict__ xq,
                 float* __restrict__ sq) {
  int row  = blockIdx.x * 4 + (threadIdx.x >> 6);
  int lane = threadIdx.x & 63;
  const float* xr = x + (size_t)row * DD + lane * 8;
  f32x4 a = *(const f32x4*)xr;
  f32x4 b = *(const f32x4*)(xr + 4);
  float s = a[0]*a[0]+a[1]*a[1]+a[2]*a[2]+a[3]*a[3]
          + b[0]*b[0]+b[1]*b[1]+b[2]*b[2]+b[3]*b[3];
  #pragma unroll
  for (int off = 1; off < 64; off <<= 1) s += __shfl_xor(s, off, 64);
  unsigned long long pk = 0;
  #pragma unroll
  for (int t = 0; t < 4; ++t) {
    __hip_fp8_e4m3 qa(a[t]), qb(b[t]);
    pk |= ((unsigned long long)qa.__x) << (8 * t);
    pk |= ((unsigned long long)qb.__x) << (8 * (t + 4));
  }
  *(unsigned long long*)(xq + (size_t)row * ROWQ + lane * 8) = pk;
  if (lane == 0) sq[row] = s;
}

// ---------------- Kernel 2: fused fp8 GEMM (X·X^T) + per-row top-2 (self excluded) -------
// block = 256 thr (4 waves) covers 128 i-rows x one j-group of 2048.
// Per wave: 2 A-sets of 16 i-rows, fp8 => 64 VGPRs total for A; each
// ds_read_b128 of a B super-chunk feeds 4 MFMAs (2 k-chunks x 2 A-sets).
// K-permutation: chunk pair (2s,2s+1) <- row bytes [s*64+quad*16, +16),
// applied identically to A and B (dot is k-permutation invariant).
// LDS chunk swizzle: within row lr, LDS chunk c holds global chunk c^(lr&7)
// -> reader hits each bank-group at most 2-way (free).
extern "C" __global__ __launch_bounds__(256, 4)
void knn_kernel(const unsigned char* __restrict__ xq, const float* __restrict__ sq,
                float* __restrict__ pv, int* __restrict__ pi) {
  __shared__ __align__(16) char lds[2 * TILEB];  // 16,384 B
  const int tid  = threadIdx.x;
  const int wave = tid >> 6;
  const int lane = tid & 63;
  const int quad = lane >> 4;
  const int r16  = lane & 15;
  const int bi   = blockIdx.x >> 3;             // 0..127
  const int bj   = blockIdx.x & 7;
  const int ibase = bi * 128 + wave * 32;       // 32 i-rows per wave
  const int jbase = bj * JRANGE;

  // A fragments: 2 sets x 8 super-chunks of 16 B (natural order == permuted order)
  l2 a0[8], a1[8];
  {
    const unsigned char* ar0 = xq + (size_t)(ibase + r16)      * ROWQ + quad * 16;
    const unsigned char* ar1 = xq + (size_t)(ibase + 16 + r16) * ROWQ + quad * 16;
    #pragma unroll
    for (int s = 0; s < 8; ++s) {
      a0[s] = *(const l2*)(ar0 + s * 64);
      a1[s] = *(const l2*)(ar1 + s * 64);
    }
  }

  // top-2 per (set s, reg r): q = s*4 + r; i-row = ibase + s*16 + quad*4 + r
  float t0v[8], t1v[8];
  int   t0i[8], t1i[8];
  #pragma unroll
  for (int q = 0; q < 8; ++q) { t0v[q] = t1v[q] = INFV; t0i[q] = t1i[q] = 0x7FFFFFFF; }

  auto stage = [&](int jt, int buf) {
    const int jrow0 = jbase + jt * BJ;
    #pragma unroll
    for (int p = 0; p < 2; ++p) {
      const int rr = wave * 4 + p * 2;                     // wave-uniform local row pair
      const int lr = rr + (lane >> 5);                     // per-lane local row
      const int u  = (lane & 31) ^ (lr & 7);               // swizzled global chunk
      const unsigned char* gsrc = xq + (size_t)(jrow0 + lr) * ROWQ + u * 16;
      char* ldst = lds + buf * TILEB + rr * ROWQ;          // wave-uniform base
      __builtin_amdgcn_global_load_lds((const __attribute__((address_space(1))) void*)gsrc,
                                       (__attribute__((address_space(3))) void*)ldst,
                                       16, 0, 0);
    }
  };

  const int sw = r16 & 7;
  stage(0, 0);
  for (int jt = 0; jt < NTILES; ++jt) {
    __syncthreads();
    if (jt + 1 < NTILES) stage(jt + 1, (jt + 1) & 1);
    const char* brow = lds + (jt & 1) * TILEB + r16 * ROWQ;
    f32x4 acc0 = {0.f, 0.f, 0.f, 0.f};
    f32x4 acc1 = {0.f, 0.f, 0.f, 0.f};
    #pragma unroll
    for (int s = 0; s < 8; ++s) {
      l2 b = *(const l2*)(brow + (((s * 4 + quad) ^ sw) * 16));
      acc0 = __builtin_amdgcn_mfma_f32_16x16x32_fp8_fp8(a0[s][0], b[0], acc0, 0, 0, 0);
      acc0 = __builtin_amdgcn_mfma_f32_16x16x32_fp8_fp8(a0[s][1], b[1], acc0, 0, 0, 0);
      acc1 = __builtin_amdgcn_mfma_f32_16x16x32_fp8_fp8(a1[s][0], b[0], acc1, 0, 0, 0);
      acc1 = __builtin_amdgcn_mfma_f32_16x16x32_fp8_fp8(a1[s][1], b[1], acc1, 0, 0, 0);
    }
    const int j = jbase + jt * BJ + r16;
    const float sqj = sq[j];
    #pragma unroll
    for (int r = 0; r < 4; ++r) {
      const int gi0 = ibase + quad * 4 + r;
      float v0 = fmaf(-2.0f, acc0[r], sqj);
      v0 = (j == gi0) ? INFV : v0;                         // exclude self
      if (v0 < t1v[r]) {                                   // j increasing: strict < keeps lowest idx on ties
        bool l0 = v0 < t0v[r];
        t1v[r] = l0 ? t0v[r] : v0;  t1i[r] = l0 ? t0i[r] : j;
        t0v[r] = l0 ? v0 : t0v[r];  t0i[r] = l0 ? j : t0i[r];
      }
      const int q = 4 + r;
      float v1 = fmaf(-2.0f, acc1[r], sqj);
      v1 = (j == gi0 + 16) ? INFV : v1;
      if (v1 < t1v[q]) {
        bool l0 = v1 < t0v[q];
        t1v[q] = l0 ? t0v[q] : v1;  t1i[q] = l0 ? t0i[q] : j;
        t0v[q] = l0 ? v1 : t0v[q];  t0i[q] = l0 ? j : t0i[q];
      }
    }
  }

  // ------- in-register butterfly merge across r16 (masks 1,2,4,8 stay in-quad) -------
  #pragma unroll
  for (int m = 1; m <= 8; m <<= 1) {
    #pragma unroll
    for (int q = 0; q < 8; ++q) {
      float ov0 = __shfl_xor(t0v[q], m, 64); int oi0 = __shfl_xor(t0i[q], m, 64);
      float ov1 = __shfl_xor(t1v[q], m, 64); int oi1 = __shfl_xor(t1i[q], m, 64);
      ins2(ov0, oi0, t0v[q], t0i[q], t1v[q], t1i[q]);
      ins2(ov1, oi1, t0v[q], t0i[q], t1v[q], t1i[q]);
    }
  }

  // lane with r16 == q writes row q's merged top-2
  #pragma unroll
  for (int q = 0; q < 8; ++q) {
    if (r16 == q) {
      int s  = q >> 2, r = q & 3;
      int gi = ibase + s * 16 + quad * 4 + r;
      int ob = (gi * JGROUPS + bj) * 2;
      pv[ob + 0] = t0v[q]; pv[ob + 1] = t1v[q];
      pi[ob + 0] = t0i[q]; pi[ob + 1] = t1i[q];
    }
  }
}

// ---------------- Kernel 3: merge partials, fp32 norms, hinge, mean ----------------
extern "C" __global__ __launch_bounds__(256)
void finalize_kernel(const float* __restrict__ x, const float* __restrict__ pos,
                     const float* __restrict__ pv, const int* __restrict__ pi,
                     float* __restrict__ out) {
  __shared__ float wsum[4];
  int i    = blockIdx.x * 4 + (threadIdx.x >> 6);
  int wave = threadIdx.x >> 6;
  int lane = threadIdx.x & 63;
  int neg = 0;
  if (lane == 0) {
    float b0 = INFV, b1 = INFV;
    int   x0 = 0x7FFFFFFF, x1 = 0x7FFFFFFF;
    #pragma unroll
    for (int s = 0; s < JGROUPS * 2; ++s) {
      ins2(pv[i * (JGROUPS * 2) + s], pi[i * (JGROUPS * 2) + s], b0, x0, b1, x1);
    }
    neg = x1;   // 2nd NN excluding self == reference idx3[:,2]
  }
  neg = __shfl(neg, 0, 64);
  const float* xr = x   + (size_t)i * DD + lane * 8;
  const float* pr = pos + (size_t)i * DD + lane * 8;
  const float* nr = x   + (size_t)neg * DD + lane * 8;
  f32x4 xa = *(const f32x4*)xr, xb4 = *(const f32x4*)(xr + 4);
  f32x4 pa = *(const f32x4*)pr, pb  = *(const f32x4*)(pr + 4);
  f32x4 na = *(const f32x4*)nr, nb  = *(const f32x4*)(nr + 4);
  float sap = 0.f, san = 0.f;
  #pragma unroll
  for (int k = 0; k < 4; ++k) {
    float d0 = xa[k]  - pa[k] + EPSV; sap = fmaf(d0, d0, sap);
    float d1 = xa[k]  - na[k] + EPSV; san = fmaf(d1, d1, san);
    float d2 = xb4[k] - pb[k] + EPSV; sap = fmaf(d2, d2, sap);
    float d3 = xb4[k] - nb[k] + EPSV; san = fmaf(d3, d3, san);
  }
  #pragma unroll
  for (int off = 1; off < 64; off <<= 1) {
    sap += __shfl_xor(sap, off, 64);
    san += __shfl_xor(san, off, 64);
  }
  if (lane == 0) {
    float l = sqrtf(sap) - sqrtf(san) + MARGINV;
    wsum[wave] = l > 0.f ? l : 0.f;
  }
  __syncthreads();
  if (threadIdx.x == 0) {
    atomicAdd(out, (wsum[0] + wsum[1] + wsum[2] + wsum[3]) * (1.0f / NN));
  }
}

// ---------------- host ----------------
extern "C" void kernel_launch(void* const* d_in, const int* in_sizes, int n_in,
                              void* d_out, int out_size, void* d_ws, size_t ws_size,
                              hipStream_t stream) {
  const float* x   = (const float*)d_in[0];
  const float* pos = (const float*)d_in[1];
  char* ws = (char*)d_ws;
  unsigned char* xq = (unsigned char*)ws;                                 // 8 MB
  float* sq = (float*)(ws + (size_t)NN * ROWQ);                           // 64 KB
  float* pv = (float*)(ws + (size_t)NN * ROWQ + (size_t)NN * 4);          // 1 MB
  int*   pi = (int*)  (ws + (size_t)NN * ROWQ + (size_t)NN * 4
                          + (size_t)NN * JGROUPS * 2 * 4);                // 1 MB

  hipMemsetAsync(d_out, 0, sizeof(float), stream);
  prep_kernel<<<NN / 4, 256, 0, stream>>>(x, xq, sq);
  knn_kernel<<<(NN / 128) * JGROUPS, 256, 0, stream>>>(xq, sq, pv, pi);
  finalize_kernel<<<NN / 4, 256, 0, stream>>>(x, pos, pv, pi, (float*)d_out);
}